// Round 3
// baseline (36.785 us; speedup 1.0000x reference)
//
#include <hip/hip_runtime.h>
#include <hip/hip_bf16.h>

#define NUM_CAMS 6
#define NQ       40000
#define MAX_LEN  10000
#define ED       256

typedef float f32x2 __attribute__((ext_vector_type(2)));

// d_out layout (float offsets)
#define OFF_IDX  0                                   // 6*10000
#define OFF_LEN  (NUM_CAMS * MAX_LEN)                // 60000, size 6
#define OFF_Q    (OFF_LEN + NUM_CAMS)                // 60006
#define OFF_REF  (OFF_Q + NUM_CAMS * MAX_LEN * ED)   // 15,420,006
#define OFF_CNT  (OFF_REF + NUM_CAMS * MAX_LEN * 8)  // 15,900,006

#define WS_LEN 0   // ws ints [0,6): per-cam len

#define GATHER_BLOCKS (NUM_CAMS * MAX_LEN / 4)   // 15000 (4 rows/block)
#define CNT_BLOCKS    ((NQ + 255) / 256)         // 157

// One block per cam: stream bev in 1024-wide chunks with a 1-chunk register
// prefetch, ballot + 16-wave LDS scan + running offset, write compacted
// indices. Early-exit once MAX_LEN valid found (valid rate ~15/16 -> ~11 of
// 40 iterations). Cold fallback fills the invalid tail when total < MAX_LEN.
__global__ __launch_bounds__(1024) void kScan(const int* __restrict__ bev,
                                              float* __restrict__ out,
                                              int* __restrict__ ws) {
    const int cam  = blockIdx.x;
    const int tid  = threadIdx.x;
    const int lane = tid & 63;
    const int wave = tid >> 6;
    __shared__ int wsum[16];
    const int* bevc = bev + (size_t)cam * NQ * 4;

    int running = 0;
    int4 cur = *reinterpret_cast<const int4*>(bevc + (size_t)tid * 4);  // tid < 1024 < NQ
    for (int base = 0; base < NQ; base += 1024) {
        const int q  = base + tid;
        const int qn = q + 1024;
        int4 nxt = make_int4(0, 0, 0, 0);
        if (qn < NQ) nxt = *reinterpret_cast<const int4*>(bevc + (size_t)qn * 4);

        const bool v = (q < NQ) && ((cur.x > 0) | (cur.y > 0) | (cur.z > 0) | (cur.w > 0));
        const unsigned long long bal = __ballot(v);
        if (lane == 0) wsum[wave] = __popcll(bal);
        __syncthreads();
        int wOff = 0, chunkTot = 0;
        #pragma unroll
        for (int w = 0; w < 16; ++w) {
            const int s = wsum[w];
            if (w < wave) wOff += s;
            chunkTot += s;
        }
        if (v) {
            const int pos = running + wOff + __popcll(bal & ((1ull << lane) - 1ull));
            if (pos < MAX_LEN) out[OFF_IDX + cam * MAX_LEN + pos] = (float)q;
        }
        running += chunkTot;
        __syncthreads();
        if (running >= MAX_LEN) break;   // uniform across block
        cur = nxt;
    }
    const int total = running;
    const int len   = total < MAX_LEN ? total : MAX_LEN;

    if (total < MAX_LEN) {               // rare path: stable invalid tail
        int runInv = 0;
        for (int base = 0; base < NQ; base += 1024) {
            const int q = base + tid;
            bool v = false;
            if (q < NQ) {
                const int4 m = *reinterpret_cast<const int4*>(bevc + (size_t)q * 4);
                v = (m.x > 0) | (m.y > 0) | (m.z > 0) | (m.w > 0);
            }
            const bool inv = (q < NQ) && !v;
            const unsigned long long bal = __ballot(inv);
            if (lane == 0) wsum[wave] = __popcll(bal);
            __syncthreads();
            int wOff = 0, chunkTot = 0;
            #pragma unroll
            for (int w = 0; w < 16; ++w) {
                const int s = wsum[w];
                if (w < wave) wOff += s;
                chunkTot += s;
            }
            if (inv) {
                const int pos = total + runInv + wOff + __popcll(bal & ((1ull << lane) - 1ull));
                if (pos < MAX_LEN) out[OFF_IDX + cam * MAX_LEN + pos] = (float)q;
            }
            runInv += chunkTot;
            __syncthreads();
            if (total + runInv >= MAX_LEN) break;
        }
    }
    if (tid == 0) {
        ws[WS_LEN + cam] = len;
        out[OFF_LEN + cam] = (float)len;
    }
}

// Blocks [0,15000): gather 4 rows/block (64 lanes per row, float2 stores —
// out regions are 8B-aligned only). Blocks [15000,15157): count_norm.
__global__ void kGather(const float* __restrict__ query, const float* __restrict__ refp,
                        float* __restrict__ out, const int* __restrict__ ws,
                        const int* __restrict__ bev) {
    const int blk = blockIdx.x;
    const int tid = threadIdx.x;
    if (blk >= GATHER_BLOCKS) {
        const int q = (blk - GATHER_BLOCKS) * 256 + tid;
        if (q < NQ) {
            int cnt = 0;
            #pragma unroll
            for (int cam = 0; cam < NUM_CAMS; ++cam) {
                const int4 m = *reinterpret_cast<const int4*>(bev + ((size_t)cam * NQ + q) * 4);
                cnt += ((m.x > 0) | (m.y > 0) | (m.z > 0) | (m.w > 0)) ? 1 : 0;
            }
            out[OFF_CNT + q] = 1.0f / fmaxf((float)cnt, 1.0f);
        }
        return;
    }
    const int rowId = blk * 4 + (tid >> 6);
    const int lane  = tid & 63;
    const int cam   = rowId / MAX_LEN;
    const int j     = rowId - cam * MAX_LEN;
    const int len   = ws[WS_LEN + cam];

    f32x2 a = (f32x2)(0.f), b = (f32x2)(0.f), r0 = (f32x2)(0.f), r1 = (f32x2)(0.f);
    if (j < len) {
        const int idx = (int)out[OFF_IDX + cam * MAX_LEN + j];
        const float4 vq = *reinterpret_cast<const float4*>(query + (size_t)idx * ED + lane * 4);
        a.x = vq.x; a.y = vq.y;
        b.x = vq.z; b.y = vq.w;
        if (lane < 2) {
            const float4 r = *reinterpret_cast<const float4*>(refp + ((size_t)cam * NQ + idx) * 8 + lane * 4);
            r0.x = r.x; r0.y = r.y;
            r1.x = r.z; r1.y = r.w;
        }
    }
    f32x2* o2 = reinterpret_cast<f32x2*>(out + OFF_Q + (size_t)rowId * ED + lane * 4);
    __builtin_nontemporal_store(a, o2);
    __builtin_nontemporal_store(b, o2 + 1);
    if (lane < 2) {
        f32x2* r2 = reinterpret_cast<f32x2*>(out + OFF_REF + (size_t)rowId * 8 + lane * 4);
        r2[0] = r0;
        r2[1] = r1;
    }
}

extern "C" void kernel_launch(void* const* d_in, const int* in_sizes, int n_in,
                              void* d_out, int out_size, void* d_ws, size_t ws_size,
                              hipStream_t stream) {
    const float* query = (const float*)d_in[0];
    const float* refp  = (const float*)d_in[1];
    const int*   bev   = (const int*)d_in[2];
    float* out = (float*)d_out;
    int*   ws  = (int*)d_ws;

    kScan<<<NUM_CAMS, 1024, 0, stream>>>(bev, out, ws);
    kGather<<<GATHER_BLOCKS + CNT_BLOCKS, 256, 0, stream>>>(query, refp, out, ws, bev);
}

// Round 4
// 35.301 us; speedup vs baseline: 1.0420x; 1.0420x over previous
//
#include <hip/hip_runtime.h>
#include <hip/hip_bf16.h>

#define NUM_CAMS 6
#define NQ       40000
#define MAX_LEN  10000
#define ED       256

typedef float f32x2 __attribute__((ext_vector_type(2)));

// d_out layout (float offsets)
#define OFF_IDX  0                                   // 6*10000
#define OFF_LEN  (NUM_CAMS * MAX_LEN)                // 60000, size 6
#define OFF_Q    (OFF_LEN + NUM_CAMS)                // 60006
#define OFF_REF  (OFF_Q + NUM_CAMS * MAX_LEN * ED)   // 15,420,006
#define OFF_CNT  (OFF_REF + NUM_CAMS * MAX_LEN * 8)  // 15,900,006

// ws layout (ints)
#define WS_LEN 0                    // [0,6)   per-cam len
#define WS_CUT 6                    // [6,12)  per-cam examined-q exclusive end
#define WS_POS 12                   // [12, 12+6*NQ) pos table
#define WS_NEED_BYTES ((WS_POS + NUM_CAMS * NQ) * 4)

#define QBLOCKS   (NQ / 4)                      // 10000 (4 q per block)
#define CNT_BLOCKS ((NQ + 255) / 256)           // 157
#define GATHER_BLOCKS (NUM_CAMS * MAX_LEN / 4)  // 15000 (fallback row-major)

// One block per cam: stream bev in 1024-wide chunks with a 1-chunk register
// prefetch, ballot + 16-wave LDS scan + running offset; write compacted idx
// (float) and, if usePos, the q->pos table. Early-exit once MAX_LEN valid
// found. Cold fallback fills the stable invalid tail when total < MAX_LEN.
__global__ __launch_bounds__(1024) void kScan(const int* __restrict__ bev,
                                              float* __restrict__ out,
                                              int* __restrict__ ws, int usePos) {
    const int cam  = blockIdx.x;
    const int tid  = threadIdx.x;
    const int lane = tid & 63;
    const int wave = tid >> 6;
    __shared__ int wsum[16];
    const int* bevc = bev + (size_t)cam * NQ * 4;

    int running = 0;
    int qEnd = NQ;
    int4 cur = *reinterpret_cast<const int4*>(bevc + (size_t)tid * 4);  // tid < NQ
    for (int base = 0; base < NQ; base += 1024) {
        const int q  = base + tid;
        const int qn = q + 1024;
        int4 nxt = make_int4(0, 0, 0, 0);
        if (qn < NQ) nxt = *reinterpret_cast<const int4*>(bevc + (size_t)qn * 4);

        const bool v = (q < NQ) && ((cur.x > 0) | (cur.y > 0) | (cur.z > 0) | (cur.w > 0));
        const unsigned long long bal = __ballot(v);
        if (lane == 0) wsum[wave] = __popcll(bal);
        __syncthreads();
        int wOff = 0, chunkTot = 0;
        #pragma unroll
        for (int w = 0; w < 16; ++w) {
            const int s = wsum[w];
            if (w < wave) wOff += s;
            chunkTot += s;
        }
        const int pos = running + wOff + __popcll(bal & ((1ull << lane) - 1ull));
        if (v && pos < MAX_LEN) out[OFF_IDX + cam * MAX_LEN + pos] = (float)q;
        if (usePos && q < NQ) ws[WS_POS + cam * NQ + q] = (v && pos < MAX_LEN) ? pos : -1;
        running += chunkTot;
        __syncthreads();
        if (running >= MAX_LEN) { qEnd = base + 1024; break; }
        cur = nxt;
    }
    const int total = running;
    const int len   = total < MAX_LEN ? total : MAX_LEN;

    if (total < MAX_LEN) {               // rare path: stable invalid tail (idx only)
        int runInv = 0;
        for (int base = 0; base < NQ; base += 1024) {
            const int q = base + tid;
            bool v = false;
            if (q < NQ) {
                const int4 m = *reinterpret_cast<const int4*>(bevc + (size_t)q * 4);
                v = (m.x > 0) | (m.y > 0) | (m.z > 0) | (m.w > 0);
            }
            const bool inv = (q < NQ) && !v;
            const unsigned long long bal = __ballot(inv);
            if (lane == 0) wsum[wave] = __popcll(bal);
            __syncthreads();
            int wOff = 0, chunkTot = 0;
            #pragma unroll
            for (int w = 0; w < 16; ++w) {
                const int s = wsum[w];
                if (w < wave) wOff += s;
                chunkTot += s;
            }
            if (inv) {
                const int pos = total + runInv + wOff + __popcll(bal & ((1ull << lane) - 1ull));
                if (pos < MAX_LEN) out[OFF_IDX + cam * MAX_LEN + pos] = (float)q;
            }
            runInv += chunkTot;
            __syncthreads();
            if (total + runInv >= MAX_LEN) break;
        }
    }
    if (tid == 0) {
        ws[WS_LEN + cam] = len;
        ws[WS_CUT + cam] = qEnd;
        out[OFF_LEN + cam] = (float)len;
    }
}

// Zero rows [len, MAX_LEN) per cam (no-op when len == MAX_LEN).
__global__ __launch_bounds__(1024) void kTail(float* __restrict__ out,
                                              const int* __restrict__ ws) {
    const int cam   = blockIdx.x;
    const int len   = ws[WS_LEN + cam];
    const int group = threadIdx.x >> 6;
    const int lane  = threadIdx.x & 63;
    const f32x2 z = (f32x2)(0.f);
    for (int j = len + group; j < MAX_LEN; j += 16) {
        f32x2* o2 = reinterpret_cast<f32x2*>(out + OFF_Q + ((size_t)cam * MAX_LEN + j) * ED + lane * 4);
        o2[0] = z; o2[1] = z;
        if (lane < 4)
            *reinterpret_cast<f32x2*>(out + OFF_REF + ((size_t)cam * MAX_LEN + j) * 8 + lane * 2) = z;
    }
}

// q-major multicast: blocks [0,10000) handle 4 q each (64 lanes per q).
// Read the 1KB query row once, scatter to every cam with pos>=0.
// Blocks [10000, 10157): count_norm.
__global__ void kGatherQ(const float* __restrict__ query, const float* __restrict__ refp,
                         float* __restrict__ out, const int* __restrict__ ws,
                         const int* __restrict__ bev) {
    const int blk = blockIdx.x;
    const int tid = threadIdx.x;
    if (blk >= QBLOCKS) {
        const int q = (blk - QBLOCKS) * 256 + tid;
        if (q < NQ) {
            int cnt = 0;
            #pragma unroll
            for (int cam = 0; cam < NUM_CAMS; ++cam) {
                const int4 m = *reinterpret_cast<const int4*>(bev + ((size_t)cam * NQ + q) * 4);
                cnt += ((m.x > 0) | (m.y > 0) | (m.z > 0) | (m.w > 0)) ? 1 : 0;
            }
            out[OFF_CNT + q] = 1.0f / fmaxf((float)cnt, 1.0f);
        }
        return;
    }
    const int group = tid >> 6;
    const int lane  = tid & 63;
    const int q     = blk * 4 + group;   // < NQ by construction

    int pos[NUM_CAMS];
    bool any = false;
    #pragma unroll
    for (int cam = 0; cam < NUM_CAMS; ++cam) {
        int p = -1;
        if (q < ws[WS_CUT + cam]) p = ws[WS_POS + cam * NQ + q];
        pos[cam] = p;
        any |= (p >= 0);
    }
    if (!any) return;

    const float4 vq = *reinterpret_cast<const float4*>(query + (size_t)q * ED + lane * 4);
    f32x2 a; a.x = vq.x; a.y = vq.y;
    f32x2 b; b.x = vq.z; b.y = vq.w;

    #pragma unroll
    for (int cam = 0; cam < NUM_CAMS; ++cam) {
        const int p = pos[cam];
        if (p >= 0) {
            f32x2* o2 = reinterpret_cast<f32x2*>(out + OFF_Q + ((size_t)cam * MAX_LEN + p) * ED + lane * 4);
            __builtin_nontemporal_store(a, o2);
            __builtin_nontemporal_store(b, o2 + 1);
            if (lane < 4) {
                const f32x2 r = *reinterpret_cast<const f32x2*>(refp + ((size_t)cam * NQ + q) * 8 + lane * 2);
                *reinterpret_cast<f32x2*>(out + OFF_REF + ((size_t)cam * MAX_LEN + p) * 8 + lane * 2) = r;
            }
        }
    }
}

// Fallback row-major gather (round-3 proven path; used if ws is too small).
__global__ void kGather(const float* __restrict__ query, const float* __restrict__ refp,
                        float* __restrict__ out, const int* __restrict__ ws,
                        const int* __restrict__ bev) {
    const int blk = blockIdx.x;
    const int tid = threadIdx.x;
    if (blk >= GATHER_BLOCKS) {
        const int q = (blk - GATHER_BLOCKS) * 256 + tid;
        if (q < NQ) {
            int cnt = 0;
            #pragma unroll
            for (int cam = 0; cam < NUM_CAMS; ++cam) {
                const int4 m = *reinterpret_cast<const int4*>(bev + ((size_t)cam * NQ + q) * 4);
                cnt += ((m.x > 0) | (m.y > 0) | (m.z > 0) | (m.w > 0)) ? 1 : 0;
            }
            out[OFF_CNT + q] = 1.0f / fmaxf((float)cnt, 1.0f);
        }
        return;
    }
    const int rowId = blk * 4 + (tid >> 6);
    const int lane  = tid & 63;
    const int cam   = rowId / MAX_LEN;
    const int j     = rowId - cam * MAX_LEN;
    const int len   = ws[WS_LEN + cam];

    f32x2 a = (f32x2)(0.f), b = (f32x2)(0.f), r0 = (f32x2)(0.f), r1 = (f32x2)(0.f);
    if (j < len) {
        const int idx = (int)out[OFF_IDX + cam * MAX_LEN + j];
        const float4 vq = *reinterpret_cast<const float4*>(query + (size_t)idx * ED + lane * 4);
        a.x = vq.x; a.y = vq.y;
        b.x = vq.z; b.y = vq.w;
        if (lane < 2) {
            const float4 r = *reinterpret_cast<const float4*>(refp + ((size_t)cam * NQ + idx) * 8 + lane * 4);
            r0.x = r.x; r0.y = r.y;
            r1.x = r.z; r1.y = r.w;
        }
    }
    f32x2* o2 = reinterpret_cast<f32x2*>(out + OFF_Q + (size_t)rowId * ED + lane * 4);
    __builtin_nontemporal_store(a, o2);
    __builtin_nontemporal_store(b, o2 + 1);
    if (lane < 2) {
        f32x2* r2 = reinterpret_cast<f32x2*>(out + OFF_REF + (size_t)rowId * 8 + lane * 4);
        r2[0] = r0;
        r2[1] = r1;
    }
}

extern "C" void kernel_launch(void* const* d_in, const int* in_sizes, int n_in,
                              void* d_out, int out_size, void* d_ws, size_t ws_size,
                              hipStream_t stream) {
    const float* query = (const float*)d_in[0];
    const float* refp  = (const float*)d_in[1];
    const int*   bev   = (const int*)d_in[2];
    float* out = (float*)d_out;
    int*   ws  = (int*)d_ws;
    const int usePos = (ws_size >= (size_t)WS_NEED_BYTES) ? 1 : 0;

    kScan<<<NUM_CAMS, 1024, 0, stream>>>(bev, out, ws, usePos);
    if (usePos) {
        kTail<<<NUM_CAMS, 1024, 0, stream>>>(out, ws);
        kGatherQ<<<QBLOCKS + CNT_BLOCKS, 256, 0, stream>>>(query, refp, out, ws, bev);
    } else {
        kGather<<<GATHER_BLOCKS + CNT_BLOCKS, 256, 0, stream>>>(query, refp, out, ws, bev);
    }
}

// Round 5
// 34.505 us; speedup vs baseline: 1.0661x; 1.0231x over previous
//
#include <hip/hip_runtime.h>
#include <hip/hip_bf16.h>

#define NUM_CAMS 6
#define NQ       40000
#define MAX_LEN  10000
#define ED       256
#define NBLK     ((NQ + 255) / 256)   // 157

typedef float f32x2 __attribute__((ext_vector_type(2)));

// d_out layout (float offsets)
#define OFF_IDX  0                                   // 6*10000
#define OFF_LEN  (NUM_CAMS * MAX_LEN)                // 60000, size 6
#define OFF_Q    (OFF_LEN + NUM_CAMS)                // 60006
#define OFF_REF  (OFF_Q + NUM_CAMS * MAX_LEN * ED)   // 15,420,006
#define OFF_CNT  (OFF_REF + NUM_CAMS * MAX_LEN * 8)  // 15,900,006

// ws layout (ints)
#define WS_OFF 0                          // [0, 6*157) block partials -> exclusive offsets
#define WS_TOT (NUM_CAMS * NBLK)          // 942, +6 per-cam totals
#define WS_LEN (WS_TOT + NUM_CAMS)        // 948, +6 per-cam len
#define WS_POS (WS_LEN + NUM_CAMS + 6)    // 960, +6*NQ q->pos table
#define WS_NEED_BYTES ((WS_POS + NUM_CAMS * NQ) * 4)

#define QBLOCKS      (NQ / 4)                       // 10000 (4 q per block)
#define TAIL_BLOCKS  (NUM_CAMS * MAX_LEN / 4)       // 15000 (tail-zero rows)
#define CNT_BLOCKS   ((NQ + 255) / 256)             // 157 (fallback count_norm)
#define GATHER_BLOCKS (NUM_CAMS * MAX_LEN / 4)      // 15000 (fallback row-major)

// 157 blocks: per-(block,cam) valid counts into ws partials + fused count_norm.
__global__ void kA_counts(const int* __restrict__ bev, float* __restrict__ out,
                          int* __restrict__ ws) {
    __shared__ int cnt[NUM_CAMS];
    const int tid = threadIdx.x;
    const int blk = blockIdx.x;
    const int q   = blk * 256 + tid;
    if (tid < NUM_CAMS) cnt[tid] = 0;
    __syncthreads();
    const int lane = tid & 63;
    const bool inb = q < NQ;
    int myCount = 0;
    #pragma unroll
    for (int cam = 0; cam < NUM_CAMS; ++cam) {
        bool v = false;
        if (inb) {
            const int4 m = *reinterpret_cast<const int4*>(bev + ((size_t)cam * NQ + q) * 4);
            v = (m.x > 0) | (m.y > 0) | (m.z > 0) | (m.w > 0);
        }
        myCount += v ? 1 : 0;
        unsigned long long bal = __ballot(v);
        if (lane == 0) atomicAdd(&cnt[cam], __popcll(bal));
    }
    if (inb) out[OFF_CNT + q] = 1.0f / fmaxf((float)myCount, 1.0f);
    __syncthreads();
    if (tid < NUM_CAMS) ws[WS_OFF + tid * NBLK + blk] = cnt[tid];
}

// 6 blocks x 64: exclusive scan of the 157 partials per cam -> offsets/total/len.
__global__ void kB_scan(float* __restrict__ out, int* __restrict__ ws) {
    const int cam  = blockIdx.x;
    const int lane = threadIdx.x;  // 64 threads
    int running = 0;
    for (int base = 0; base < NBLK; base += 64) {
        const int i = base + lane;
        int val = (i < NBLK) ? ws[WS_OFF + cam * NBLK + i] : 0;
        int v = val;
        for (int d = 1; d < 64; d <<= 1) {
            int n = __shfl_up(v, d, 64);
            if (lane >= d) v += n;
        }
        if (i < NBLK) ws[WS_OFF + cam * NBLK + i] = v - val + running;  // exclusive
        running += __shfl(v, 63, 64);
    }
    if (lane == 0) {
        ws[WS_TOT + cam] = running;
        const int len = running < MAX_LEN ? running : MAX_LEN;
        ws[WS_LEN + cam] = len;
        out[OFF_LEN + cam] = (float)len;
    }
}

// (157,6) blocks: recompute valid, block-local ballot scan + global offset,
// write stable-partition indexes and (usePos) the q->pos multicast table.
__global__ void kC_indexes(const int* __restrict__ bev, float* __restrict__ out,
                           int* __restrict__ ws, int usePos) {
    const int blk = blockIdx.x;
    const int cam = blockIdx.y;
    const int tid = threadIdx.x;
    const int q    = blk * 256 + tid;
    const int lane = tid & 63;
    const int wave = tid >> 6;
    const bool inb = q < NQ;
    bool v = false;
    if (inb) {
        const int4 m = *reinterpret_cast<const int4*>(bev + ((size_t)cam * NQ + q) * 4);
        v = (m.x > 0) | (m.y > 0) | (m.z > 0) | (m.w > 0);
    }
    const unsigned long long bal = __ballot(v);
    __shared__ int waveSums[4];
    if (lane == 0) waveSums[wave] = __popcll(bal);
    __syncthreads();
    int waveOff = 0;
    #pragma unroll
    for (int w = 0; w < 4; ++w)
        if (w < wave) waveOff += waveSums[w];
    const int prefix   = __popcll(bal & ((1ull << lane) - 1ull));
    const int blockOff = ws[WS_OFF + cam * NBLK + blk];
    const int total    = ws[WS_TOT + cam];
    if (inb) {
        const int vb  = blockOff + waveOff + prefix;      // valid strictly before q
        const int pos = v ? vb : (total + (q - vb));      // stable partition position
        if (pos < MAX_LEN) out[OFF_IDX + cam * MAX_LEN + pos] = (float)q;
        if (usePos) ws[WS_POS + cam * NQ + q] = (v && vb < MAX_LEN) ? vb : -1;
    }
}

// Blocks [0,10000): q-major multicast — 4 q/block, 64 lanes/q; read the 1KB
// query row once, NT-scatter to every cam with pos>=0 (8B stores: OFF_Q*4%16==8).
// Blocks [10000,25000): zero tail rows [len, MAX_LEN) (immediate exit when full).
__global__ void kGatherQ(const float* __restrict__ query, const float* __restrict__ refp,
                         float* __restrict__ out, const int* __restrict__ ws) {
    const int blk   = blockIdx.x;
    const int tid   = threadIdx.x;
    const int group = tid >> 6;
    const int lane  = tid & 63;
    if (blk >= QBLOCKS) {
        const int rowId = (blk - QBLOCKS) * 4 + group;
        const int cam   = rowId / MAX_LEN;
        const int j     = rowId - cam * MAX_LEN;
        if (j < ws[WS_LEN + cam]) return;
        const f32x2 z = (f32x2)(0.f);
        f32x2* o2 = reinterpret_cast<f32x2*>(out + OFF_Q + (size_t)rowId * ED + lane * 4);
        o2[0] = z; o2[1] = z;
        if (lane < 4)
            *reinterpret_cast<f32x2*>(out + OFF_REF + (size_t)rowId * 8 + lane * 2) = z;
        return;
    }
    const int q = blk * 4 + group;   // < NQ

    int pos[NUM_CAMS];
    bool any = false;
    #pragma unroll
    for (int cam = 0; cam < NUM_CAMS; ++cam) {
        const int p = ws[WS_POS + cam * NQ + q];
        pos[cam] = p;
        any |= (p >= 0);
    }
    if (!any) return;

    const float4 vq = *reinterpret_cast<const float4*>(query + (size_t)q * ED + lane * 4);
    f32x2 a; a.x = vq.x; a.y = vq.y;
    f32x2 b; b.x = vq.z; b.y = vq.w;

    #pragma unroll
    for (int cam = 0; cam < NUM_CAMS; ++cam) {
        const int p = pos[cam];
        if (p >= 0) {
            f32x2* o2 = reinterpret_cast<f32x2*>(out + OFF_Q + ((size_t)cam * MAX_LEN + p) * ED + lane * 4);
            __builtin_nontemporal_store(a, o2);
            __builtin_nontemporal_store(b, o2 + 1);
            if (lane < 4) {
                const f32x2 r = *reinterpret_cast<const f32x2*>(refp + ((size_t)cam * NQ + q) * 8 + lane * 2);
                *reinterpret_cast<f32x2*>(out + OFF_REF + ((size_t)cam * MAX_LEN + p) * 8 + lane * 2) = r;
            }
        }
    }
}

// Fallback row-major gather (+count_norm) if ws too small for the pos table.
__global__ void kGather(const float* __restrict__ query, const float* __restrict__ refp,
                        float* __restrict__ out, const int* __restrict__ ws,
                        const int* __restrict__ bev) {
    const int blk = blockIdx.x;
    const int tid = threadIdx.x;
    if (blk >= GATHER_BLOCKS) {
        const int q = (blk - GATHER_BLOCKS) * 256 + tid;
        if (q < NQ) {
            int cnt = 0;
            #pragma unroll
            for (int cam = 0; cam < NUM_CAMS; ++cam) {
                const int4 m = *reinterpret_cast<const int4*>(bev + ((size_t)cam * NQ + q) * 4);
                cnt += ((m.x > 0) | (m.y > 0) | (m.z > 0) | (m.w > 0)) ? 1 : 0;
            }
            out[OFF_CNT + q] = 1.0f / fmaxf((float)cnt, 1.0f);
        }
        return;
    }
    const int rowId = blk * 4 + (tid >> 6);
    const int lane  = tid & 63;
    const int cam   = rowId / MAX_LEN;
    const int j     = rowId - cam * MAX_LEN;
    const int len   = ws[WS_LEN + cam];

    f32x2 a = (f32x2)(0.f), b = (f32x2)(0.f), r0 = (f32x2)(0.f), r1 = (f32x2)(0.f);
    if (j < len) {
        const int idx = (int)out[OFF_IDX + cam * MAX_LEN + j];
        const float4 vq = *reinterpret_cast<const float4*>(query + (size_t)idx * ED + lane * 4);
        a.x = vq.x; a.y = vq.y;
        b.x = vq.z; b.y = vq.w;
        if (lane < 2) {
            const float4 r = *reinterpret_cast<const float4*>(refp + ((size_t)cam * NQ + idx) * 8 + lane * 4);
            r0.x = r.x; r0.y = r.y;
            r1.x = r.z; r1.y = r.w;
        }
    }
    f32x2* o2 = reinterpret_cast<f32x2*>(out + OFF_Q + (size_t)rowId * ED + lane * 4);
    __builtin_nontemporal_store(a, o2);
    __builtin_nontemporal_store(b, o2 + 1);
    if (lane < 2) {
        f32x2* r2 = reinterpret_cast<f32x2*>(out + OFF_REF + (size_t)rowId * 8 + lane * 4);
        r2[0] = r0;
        r2[1] = r1;
    }
}

extern "C" void kernel_launch(void* const* d_in, const int* in_sizes, int n_in,
                              void* d_out, int out_size, void* d_ws, size_t ws_size,
                              hipStream_t stream) {
    const float* query = (const float*)d_in[0];
    const float* refp  = (const float*)d_in[1];
    const int*   bev   = (const int*)d_in[2];
    float* out = (float*)d_out;
    int*   ws  = (int*)d_ws;
    const int usePos = (ws_size >= (size_t)WS_NEED_BYTES) ? 1 : 0;

    kA_counts<<<NBLK, 256, 0, stream>>>(bev, out, ws);
    kB_scan<<<NUM_CAMS, 64, 0, stream>>>(out, ws);
    kC_indexes<<<dim3(NBLK, NUM_CAMS), 256, 0, stream>>>(bev, out, ws, usePos);
    if (usePos) {
        kGatherQ<<<QBLOCKS + TAIL_BLOCKS, 256, 0, stream>>>(query, refp, out, ws);
    } else {
        kGather<<<GATHER_BLOCKS + CNT_BLOCKS, 256, 0, stream>>>(query, refp, out, ws, bev);
    }
}

// Round 6
// 31.201 us; speedup vs baseline: 1.1790x; 1.1059x over previous
//
#include <hip/hip_runtime.h>
#include <hip/hip_bf16.h>

#define NUM_CAMS 6
#define NQ       40000
#define MAX_LEN  10000
#define ED       256
#define NBLK     ((NQ + 255) / 256)   // 157

typedef float f32x2 __attribute__((ext_vector_type(2)));

// d_out layout (float offsets)
#define OFF_IDX  0                                   // 6*10000
#define OFF_LEN  (NUM_CAMS * MAX_LEN)                // 60000, size 6
#define OFF_Q    (OFF_LEN + NUM_CAMS)                // 60006
#define OFF_REF  (OFF_Q + NUM_CAMS * MAX_LEN * ED)   // 15,420,006
#define OFF_CNT  (OFF_REF + NUM_CAMS * MAX_LEN * 8)  // 15,900,006

// ws layout (ints)
#define WS_OFF 0                          // [0, 6*157) per-(cam,block) raw valid counts
#define WS_LEN (NUM_CAMS * NBLK)          // 942, +6 per-cam len
#define WS_POS (WS_LEN + NUM_CAMS + 4)    // 952, +6*NQ q->pos table
#define WS_NEED_BYTES ((WS_POS + NUM_CAMS * NQ) * 4)

#define QBLOCKS      (NQ / 4)                       // 10000 (4 q per block)
#define TAIL_BLOCKS  (NUM_CAMS * MAX_LEN / 4)       // 15000 (tail-zero rows)
#define CNT_BLOCKS   ((NQ + 255) / 256)             // 157 (fallback count_norm)
#define GATHER_BLOCKS (NUM_CAMS * MAX_LEN / 4)      // 15000 (fallback row-major)

// 157 blocks: per-(block,cam) valid counts into ws partials + fused count_norm.
__global__ void kA_counts(const int* __restrict__ bev, float* __restrict__ out,
                          int* __restrict__ ws) {
    __shared__ int cnt[NUM_CAMS];
    const int tid = threadIdx.x;
    const int blk = blockIdx.x;
    const int q   = blk * 256 + tid;
    if (tid < NUM_CAMS) cnt[tid] = 0;
    __syncthreads();
    const int lane = tid & 63;
    const bool inb = q < NQ;
    int myCount = 0;
    #pragma unroll
    for (int cam = 0; cam < NUM_CAMS; ++cam) {
        bool v = false;
        if (inb) {
            const int4 m = *reinterpret_cast<const int4*>(bev + ((size_t)cam * NQ + q) * 4);
            v = (m.x > 0) | (m.y > 0) | (m.z > 0) | (m.w > 0);
        }
        myCount += v ? 1 : 0;
        unsigned long long bal = __ballot(v);
        if (lane == 0) atomicAdd(&cnt[cam], __popcll(bal));
    }
    if (inb) out[OFF_CNT + q] = 1.0f / fmaxf((float)myCount, 1.0f);
    __syncthreads();
    if (tid < NUM_CAMS) ws[WS_OFF + tid * NBLK + blk] = cnt[tid];
}

// (157,6) blocks: block-reduce the 157 raw partials (masked: < blk) to get this
// block's exclusive offset AND the cam total; then ballot-scan to write stable
// partition indexes and the q->pos multicast table. Replaces the old kB+kC.
__global__ void kBC_indexes(const int* __restrict__ bev, float* __restrict__ out,
                            int* __restrict__ ws, int usePos) {
    const int blk = blockIdx.x;
    const int cam = blockIdx.y;
    const int tid = threadIdx.x;
    const int lane = tid & 63;
    const int wave = tid >> 6;

    // --- offsets from raw partials ---
    const int part = (tid < NBLK) ? ws[WS_OFF + cam * NBLK + tid] : 0;
    int t = part;                       // -> total over all blocks
    int o = (tid < blk) ? part : 0;     // -> exclusive offset for this block
    #pragma unroll
    for (int d = 1; d < 64; d <<= 1) {
        t += __shfl_xor(t, d, 64);
        o += __shfl_xor(o, d, 64);
    }
    __shared__ int sT[4], sO[4];
    if (lane == 0) { sT[wave] = t; sO[wave] = o; }
    __syncthreads();
    const int total    = sT[0] + sT[1] + sT[2] + sT[3];
    const int blockOff = sO[0] + sO[1] + sO[2] + sO[3];

    if (blk == 0 && tid == 0) {
        const int len = total < MAX_LEN ? total : MAX_LEN;
        ws[WS_LEN + cam] = len;
        out[OFF_LEN + cam] = (float)len;
    }

    // --- per-q positions ---
    const int q   = blk * 256 + tid;
    const bool inb = q < NQ;
    bool v = false;
    if (inb) {
        const int4 m = *reinterpret_cast<const int4*>(bev + ((size_t)cam * NQ + q) * 4);
        v = (m.x > 0) | (m.y > 0) | (m.z > 0) | (m.w > 0);
    }
    const unsigned long long bal = __ballot(v);
    __shared__ int waveSums[4];
    if (lane == 0) waveSums[wave] = __popcll(bal);
    __syncthreads();
    int waveOff = 0;
    #pragma unroll
    for (int w = 0; w < 4; ++w)
        if (w < wave) waveOff += waveSums[w];
    const int prefix = __popcll(bal & ((1ull << lane) - 1ull));
    if (inb) {
        const int vb  = blockOff + waveOff + prefix;      // valid strictly before q
        const int pos = v ? vb : (total + (q - vb));      // stable partition position
        if (pos < MAX_LEN) out[OFF_IDX + cam * MAX_LEN + pos] = (float)q;
        if (usePos) ws[WS_POS + cam * NQ + q] = (v && vb < MAX_LEN) ? vb : -1;
    }
}

// Blocks [0,10000): q-major multicast — 4 q/block, 64 lanes/q; read the 1KB
// query row once, scatter to every cam with pos>=0 (plain 8B stores; the out
// regions are 8B-aligned, and L2 write-combines the stream).
// Blocks [10000,25000): zero tail rows [len, MAX_LEN) (immediate exit when full).
__global__ void kGatherQ(const float* __restrict__ query, const float* __restrict__ refp,
                         float* __restrict__ out, const int* __restrict__ ws) {
    const int blk   = blockIdx.x;
    const int tid   = threadIdx.x;
    const int group = tid >> 6;
    const int lane  = tid & 63;
    if (blk >= QBLOCKS) {
        const int rowId = (blk - QBLOCKS) * 4 + group;
        const int cam   = rowId / MAX_LEN;
        const int j     = rowId - cam * MAX_LEN;
        if (j < ws[WS_LEN + cam]) return;
        const f32x2 z = (f32x2)(0.f);
        f32x2* o2 = reinterpret_cast<f32x2*>(out + OFF_Q + (size_t)rowId * ED + lane * 4);
        o2[0] = z; o2[1] = z;
        if (lane < 4)
            *reinterpret_cast<f32x2*>(out + OFF_REF + (size_t)rowId * 8 + lane * 2) = z;
        return;
    }
    const int q = blk * 4 + group;   // < NQ

    int pos[NUM_CAMS];
    bool any = false;
    #pragma unroll
    for (int cam = 0; cam < NUM_CAMS; ++cam) {
        const int p = ws[WS_POS + cam * NQ + q];
        pos[cam] = p;
        any |= (p >= 0);
    }
    if (!any) return;

    const float4 vq = *reinterpret_cast<const float4*>(query + (size_t)q * ED + lane * 4);
    f32x2 a; a.x = vq.x; a.y = vq.y;
    f32x2 b; b.x = vq.z; b.y = vq.w;

    #pragma unroll
    for (int cam = 0; cam < NUM_CAMS; ++cam) {
        const int p = pos[cam];
        if (p >= 0) {
            f32x2* o2 = reinterpret_cast<f32x2*>(out + OFF_Q + ((size_t)cam * MAX_LEN + p) * ED + lane * 4);
            o2[0] = a;
            o2[1] = b;
            if (lane < 4) {
                const f32x2 r = *reinterpret_cast<const f32x2*>(refp + ((size_t)cam * NQ + q) * 8 + lane * 2);
                *reinterpret_cast<f32x2*>(out + OFF_REF + ((size_t)cam * MAX_LEN + p) * 8 + lane * 2) = r;
            }
        }
    }
}

// Fallback row-major gather (+count_norm) if ws too small for the pos table.
__global__ void kGather(const float* __restrict__ query, const float* __restrict__ refp,
                        float* __restrict__ out, const int* __restrict__ ws,
                        const int* __restrict__ bev) {
    const int blk = blockIdx.x;
    const int tid = threadIdx.x;
    if (blk >= GATHER_BLOCKS) {
        const int q = (blk - GATHER_BLOCKS) * 256 + tid;
        if (q < NQ) {
            int cnt = 0;
            #pragma unroll
            for (int cam = 0; cam < NUM_CAMS; ++cam) {
                const int4 m = *reinterpret_cast<const int4*>(bev + ((size_t)cam * NQ + q) * 4);
                cnt += ((m.x > 0) | (m.y > 0) | (m.z > 0) | (m.w > 0)) ? 1 : 0;
            }
            out[OFF_CNT + q] = 1.0f / fmaxf((float)cnt, 1.0f);
        }
        return;
    }
    const int rowId = blk * 4 + (tid >> 6);
    const int lane  = tid & 63;
    const int cam   = rowId / MAX_LEN;
    const int j     = rowId - cam * MAX_LEN;
    const int len   = ws[WS_LEN + cam];

    f32x2 a = (f32x2)(0.f), b = (f32x2)(0.f), r0 = (f32x2)(0.f), r1 = (f32x2)(0.f);
    if (j < len) {
        const int idx = (int)out[OFF_IDX + cam * MAX_LEN + j];
        const float4 vq = *reinterpret_cast<const float4*>(query + (size_t)idx * ED + lane * 4);
        a.x = vq.x; a.y = vq.y;
        b.x = vq.z; b.y = vq.w;
        if (lane < 2) {
            const float4 r = *reinterpret_cast<const float4*>(refp + ((size_t)cam * NQ + idx) * 8 + lane * 4);
            r0.x = r.x; r0.y = r.y;
            r1.x = r.z; r1.y = r.w;
        }
    }
    f32x2* o2 = reinterpret_cast<f32x2*>(out + OFF_Q + (size_t)rowId * ED + lane * 4);
    o2[0] = a;
    o2[1] = b;
    if (lane < 2) {
        f32x2* r2 = reinterpret_cast<f32x2*>(out + OFF_REF + (size_t)rowId * 8 + lane * 4);
        r2[0] = r0;
        r2[1] = r1;
    }
}

extern "C" void kernel_launch(void* const* d_in, const int* in_sizes, int n_in,
                              void* d_out, int out_size, void* d_ws, size_t ws_size,
                              hipStream_t stream) {
    const float* query = (const float*)d_in[0];
    const float* refp  = (const float*)d_in[1];
    const int*   bev   = (const int*)d_in[2];
    float* out = (float*)d_out;
    int*   ws  = (int*)d_ws;
    const int usePos = (ws_size >= (size_t)WS_NEED_BYTES) ? 1 : 0;

    kA_counts<<<NBLK, 256, 0, stream>>>(bev, out, ws);
    kBC_indexes<<<dim3(NBLK, NUM_CAMS), 256, 0, stream>>>(bev, out, ws, usePos);
    if (usePos) {
        kGatherQ<<<QBLOCKS + TAIL_BLOCKS, 256, 0, stream>>>(query, refp, out, ws);
    } else {
        kGather<<<GATHER_BLOCKS + CNT_BLOCKS, 256, 0, stream>>>(query, refp, out, ws, bev);
    }
}

// Round 7
// 31.045 us; speedup vs baseline: 1.1849x; 1.0050x over previous
//
#include <hip/hip_runtime.h>
#include <hip/hip_bf16.h>

#define NUM_CAMS 6
#define NQ       40000
#define MAX_LEN  10000
#define ED       256
#define NBLK     ((NQ + 255) / 256)   // 157

typedef float f32x2 __attribute__((ext_vector_type(2)));

// d_out layout (float offsets)
#define OFF_IDX  0                                   // 6*10000
#define OFF_LEN  (NUM_CAMS * MAX_LEN)                // 60000, size 6
#define OFF_Q    (OFF_LEN + NUM_CAMS)                // 60006
#define OFF_REF  (OFF_Q + NUM_CAMS * MAX_LEN * ED)   // 15,420,006
#define OFF_CNT  (OFF_REF + NUM_CAMS * MAX_LEN * 8)  // 15,900,006

// ws layout (ints)
#define WS_OFF    0                               // [0, 942) per-(cam,block) valid counts
#define WS_MASK_I 960                             // u64 ballot masks, byte off 3840 (8B aligned)
#define WS_MASK_N (NUM_CAMS * NBLK * 4)           // 3768 u64 = 7536 ints
#define WS_LEN    (WS_MASK_I + 2 * WS_MASK_N)     // 8496, +6 per-cam len
#define WS_POS    (WS_LEN + 8)                    // 8504, +6*NQ q->pos table
#define WS_NEED_BYTES ((WS_POS + NUM_CAMS * NQ) * 4)

#define QBLOCKS      (NQ / 4)                       // 10000 q-group items (4 q each)
#define TAIL_BLOCKS  (NUM_CAMS * MAX_LEN / 4)       // 15000 tail items (4 rows each)
#define GATHER_GRID  2048                           // persistent blocks for kGatherQ
#define CNT_BLOCKS   ((NQ + 255) / 256)             // 157 (fallback count_norm)
#define GATHER_BLOCKS (NUM_CAMS * MAX_LEN / 4)      // 15000 (fallback row-major)

// 157 blocks: per-(block,cam) valid counts + ballot masks + fused count_norm.
__global__ void kA_counts(const int* __restrict__ bev, float* __restrict__ out,
                          int* __restrict__ ws, int usePos) {
    __shared__ int cnt[NUM_CAMS];
    const int tid = threadIdx.x;
    const int blk = blockIdx.x;
    const int q   = blk * 256 + tid;
    if (tid < NUM_CAMS) cnt[tid] = 0;
    __syncthreads();
    const int lane = tid & 63;
    const int wave = tid >> 6;
    const bool inb = q < NQ;
    unsigned long long* wsm = reinterpret_cast<unsigned long long*>(ws + WS_MASK_I);
    int myCount = 0;
    #pragma unroll
    for (int cam = 0; cam < NUM_CAMS; ++cam) {
        bool v = false;
        if (inb) {
            const int4 m = *reinterpret_cast<const int4*>(bev + ((size_t)cam * NQ + q) * 4);
            v = (m.x > 0) | (m.y > 0) | (m.z > 0) | (m.w > 0);
        }
        myCount += v ? 1 : 0;
        const unsigned long long bal = __ballot(v);
        if (lane == 0) {
            atomicAdd(&cnt[cam], __popcll(bal));
            if (usePos) wsm[((size_t)cam * NBLK + blk) * 4 + wave] = bal;
        }
    }
    if (inb) out[OFF_CNT + q] = 1.0f / fmaxf((float)myCount, 1.0f);
    __syncthreads();
    if (tid < NUM_CAMS) ws[WS_OFF + tid * NBLK + blk] = cnt[tid];
}

// (157,6) blocks: wave-reduce partials -> exclusive offset + total; valid bits
// come from the stored ballot masks (no bev re-read). Writes idx, len, pos.
__global__ void kBC_indexes(const int* __restrict__ bev, float* __restrict__ out,
                            int* __restrict__ ws, int usePos) {
    const int blk = blockIdx.x;
    const int cam = blockIdx.y;
    const int tid = threadIdx.x;
    const int lane = tid & 63;
    const int wave = tid >> 6;

    // --- offsets from raw partials ---
    const int part = (tid < NBLK) ? ws[WS_OFF + cam * NBLK + tid] : 0;
    int t = part;                       // -> total over all blocks
    int o = (tid < blk) ? part : 0;     // -> exclusive offset for this block
    #pragma unroll
    for (int d = 1; d < 64; d <<= 1) {
        t += __shfl_xor(t, d, 64);
        o += __shfl_xor(o, d, 64);
    }
    __shared__ int sT[4], sO[4], waveSums[4];

    // --- valid bits ---
    unsigned long long mask;
    if (usePos) {
        const unsigned long long* wsm =
            reinterpret_cast<const unsigned long long*>(ws + WS_MASK_I);
        mask = wsm[((size_t)cam * NBLK + blk) * 4 + wave];
    } else {
        const int q = blk * 256 + tid;
        bool v = false;
        if (q < NQ) {
            const int4 m = *reinterpret_cast<const int4*>(bev + ((size_t)cam * NQ + q) * 4);
            v = (m.x > 0) | (m.y > 0) | (m.z > 0) | (m.w > 0);
        }
        mask = __ballot(v);
    }
    if (lane == 0) { sT[wave] = t; sO[wave] = o; waveSums[wave] = __popcll(mask); }
    __syncthreads();
    const int total    = sT[0] + sT[1] + sT[2] + sT[3];
    const int blockOff = sO[0] + sO[1] + sO[2] + sO[3];

    if (blk == 0 && tid == 0) {
        const int len = total < MAX_LEN ? total : MAX_LEN;
        ws[WS_LEN + cam] = len;
        out[OFF_LEN + cam] = (float)len;
    }

    const int q = blk * 256 + tid;
    if (q < NQ) {
        int waveOff = 0;
        #pragma unroll
        for (int w = 0; w < 4; ++w)
            if (w < wave) waveOff += waveSums[w];
        const bool v     = (mask >> lane) & 1ull;
        const int prefix = __popcll(mask & ((1ull << lane) - 1ull));
        const int vb  = blockOff + waveOff + prefix;      // valid strictly before q
        const int pos = v ? vb : (total + (q - vb));      // stable partition position
        if (pos < MAX_LEN) out[OFF_IDX + cam * MAX_LEN + pos] = (float)q;
        if (usePos) ws[WS_POS + cam * NQ + q] = (v && vb < MAX_LEN) ? vb : -1;
    }
}

// Persistent grid-stride: items [0,10000) = q-major multicast (4 q/item, 64
// lanes/q: read the 1KB query row once, scatter to every cam with pos>=0);
// items [10000,25000) = tail rows [len, MAX_LEN) zeroing (4 rows/item).
__global__ void kGatherQ(const float* __restrict__ query, const float* __restrict__ refp,
                         float* __restrict__ out, const int* __restrict__ ws) {
    const int tid   = threadIdx.x;
    const int group = tid >> 6;
    const int lane  = tid & 63;
    for (int item = blockIdx.x; item < QBLOCKS + TAIL_BLOCKS; item += gridDim.x) {
        if (item < QBLOCKS) {
            const int q = item * 4 + group;   // < NQ
            int pos[NUM_CAMS];
            bool any = false;
            #pragma unroll
            for (int cam = 0; cam < NUM_CAMS; ++cam) {
                const int p = ws[WS_POS + cam * NQ + q];
                pos[cam] = p;
                any |= (p >= 0);
            }
            if (!any) continue;

            const float4 vq = *reinterpret_cast<const float4*>(query + (size_t)q * ED + lane * 4);
            f32x2 a; a.x = vq.x; a.y = vq.y;
            f32x2 b; b.x = vq.z; b.y = vq.w;

            #pragma unroll
            for (int cam = 0; cam < NUM_CAMS; ++cam) {
                const int p = pos[cam];
                if (p >= 0) {
                    f32x2* o2 = reinterpret_cast<f32x2*>(out + OFF_Q + ((size_t)cam * MAX_LEN + p) * ED + lane * 4);
                    o2[0] = a;
                    o2[1] = b;
                    if (lane < 4) {
                        const f32x2 r = *reinterpret_cast<const f32x2*>(refp + ((size_t)cam * NQ + q) * 8 + lane * 2);
                        *reinterpret_cast<f32x2*>(out + OFF_REF + ((size_t)cam * MAX_LEN + p) * 8 + lane * 2) = r;
                    }
                }
            }
        } else {
            const int rowId = (item - QBLOCKS) * 4 + group;
            const int cam   = rowId / MAX_LEN;
            const int j     = rowId - cam * MAX_LEN;
            if (j < ws[WS_LEN + cam]) continue;
            const f32x2 z = (f32x2)(0.f);
            f32x2* o2 = reinterpret_cast<f32x2*>(out + OFF_Q + (size_t)rowId * ED + lane * 4);
            o2[0] = z; o2[1] = z;
            if (lane < 4)
                *reinterpret_cast<f32x2*>(out + OFF_REF + (size_t)rowId * 8 + lane * 2) = z;
        }
    }
}

// Fallback row-major gather (+count_norm) if ws too small for masks+pos table.
__global__ void kGather(const float* __restrict__ query, const float* __restrict__ refp,
                        float* __restrict__ out, const int* __restrict__ ws,
                        const int* __restrict__ bev) {
    const int blk = blockIdx.x;
    const int tid = threadIdx.x;
    if (blk >= GATHER_BLOCKS) {
        const int q = (blk - GATHER_BLOCKS) * 256 + tid;
        if (q < NQ) {
            int cnt = 0;
            #pragma unroll
            for (int cam = 0; cam < NUM_CAMS; ++cam) {
                const int4 m = *reinterpret_cast<const int4*>(bev + ((size_t)cam * NQ + q) * 4);
                cnt += ((m.x > 0) | (m.y > 0) | (m.z > 0) | (m.w > 0)) ? 1 : 0;
            }
            out[OFF_CNT + q] = 1.0f / fmaxf((float)cnt, 1.0f);
        }
        return;
    }
    const int rowId = blk * 4 + (tid >> 6);
    const int lane  = tid & 63;
    const int cam   = rowId / MAX_LEN;
    const int j     = rowId - cam * MAX_LEN;
    const int len   = ws[WS_LEN + cam];

    f32x2 a = (f32x2)(0.f), b = (f32x2)(0.f), r0 = (f32x2)(0.f), r1 = (f32x2)(0.f);
    if (j < len) {
        const int idx = (int)out[OFF_IDX + cam * MAX_LEN + j];
        const float4 vq = *reinterpret_cast<const float4*>(query + (size_t)idx * ED + lane * 4);
        a.x = vq.x; a.y = vq.y;
        b.x = vq.z; b.y = vq.w;
        if (lane < 2) {
            const float4 r = *reinterpret_cast<const float4*>(refp + ((size_t)cam * NQ + idx) * 8 + lane * 4);
            r0.x = r.x; r0.y = r.y;
            r1.x = r.z; r1.y = r.w;
        }
    }
    f32x2* o2 = reinterpret_cast<f32x2*>(out + OFF_Q + (size_t)rowId * ED + lane * 4);
    o2[0] = a;
    o2[1] = b;
    if (lane < 2) {
        f32x2* r2 = reinterpret_cast<f32x2*>(out + OFF_REF + (size_t)rowId * 8 + lane * 4);
        r2[0] = r0;
        r2[1] = r1;
    }
}

extern "C" void kernel_launch(void* const* d_in, const int* in_sizes, int n_in,
                              void* d_out, int out_size, void* d_ws, size_t ws_size,
                              hipStream_t stream) {
    const float* query = (const float*)d_in[0];
    const float* refp  = (const float*)d_in[1];
    const int*   bev   = (const int*)d_in[2];
    float* out = (float*)d_out;
    int*   ws  = (int*)d_ws;
    const int usePos = (ws_size >= (size_t)WS_NEED_BYTES) ? 1 : 0;

    kA_counts<<<NBLK, 256, 0, stream>>>(bev, out, ws, usePos);
    kBC_indexes<<<dim3(NBLK, NUM_CAMS), 256, 0, stream>>>(bev, out, ws, usePos);
    if (usePos) {
        kGatherQ<<<GATHER_GRID, 256, 0, stream>>>(query, refp, out, ws);
    } else {
        kGather<<<GATHER_BLOCKS + CNT_BLOCKS, 256, 0, stream>>>(query, refp, out, ws, bev);
    }
}